// Round 3
// baseline (523.435 us; speedup 1.0000x reference)
//
#include <hip/hip_runtime.h>

// ---------------------------------------------------------------------------
// MHA forward. B=2 S=4096 D=1024 H=16 DK=64. bf16 MFMA 16x16x32, fp32 acc.
// R3: global_load_lds (width 16) staging everywhere; attn K/V double-buffered
// with ONE barrier/iter (DMA issued right after barrier, drained at next —
// latency hidden behind compute); swizzled-source DMA keeps frag reads
// conflict-free; Q frags direct from global (no Q LDS); exp2-domain softmax
// (log2e folded into Q projection); O-rescale skipped when max unchanged.
// ---------------------------------------------------------------------------

typedef __bf16 bf16x8 __attribute__((ext_vector_type(8)));
typedef __bf16 bf16x4 __attribute__((ext_vector_type(4)));
typedef float  f32x4  __attribute__((ext_vector_type(4)));

#define MFMA16(a, b, c) __builtin_amdgcn_mfma_f32_16x16x32_bf16(a, b, c, 0, 0, 0)

constexpr int D_MODEL = 1024;
constexpr int SEQ     = 4096;
constexpr int BATCH   = 2;
constexpr int DKH     = 64;
constexpr int MROWS   = BATCH * SEQ;  // 8192
constexpr int QT      = 256;          // q rows per attn block
constexpr int LROW    = 72;           // padded LDS row stride for Ps
// softmax in exp2 domain: fold 1/sqrt(64) * log2(e) into Q projection
constexpr float QSCALE = 0.125f * 1.4426950408889634f;

__device__ __forceinline__ void gll16(const void* g, void* l) {
  __builtin_amdgcn_global_load_lds(
      (const __attribute__((address_space(1))) void*)g,
      (__attribute__((address_space(3))) void*)l, 16, 0, 0);
}

// ---------------------------------------------------------------- cast kernels
__global__ void cast_x3(const float* __restrict__ a, const float* __restrict__ b,
                        const float* __restrict__ c, __bf16* __restrict__ out) {
  const float* in = blockIdx.y == 0 ? a : (blockIdx.y == 1 ? b : c);
  __bf16* o = out + (size_t)blockIdx.y * MROWS * D_MODEL;
  int i = (blockIdx.x * 256 + threadIdx.x) * 4;
  float4 v = *(const float4*)(in + i);
  bf16x4 ov;
  ov[0] = (__bf16)v.x; ov[1] = (__bf16)v.y; ov[2] = (__bf16)v.z; ov[3] = (__bf16)v.w;
  *(bf16x4*)(o + i) = ov;
}

__global__ void cast_w4(const float* __restrict__ a, const float* __restrict__ b,
                        const float* __restrict__ c, const float* __restrict__ d,
                        __bf16* __restrict__ out) {
  const float* in = blockIdx.y == 0 ? a
                    : (blockIdx.y == 1 ? b : (blockIdx.y == 2 ? c : d));
  __bf16* o = out + (size_t)blockIdx.y * D_MODEL * D_MODEL;
  int i = (blockIdx.x * 256 + threadIdx.x) * 4;
  float4 v = *(const float4*)(in + i);
  bf16x4 ov;
  ov[0] = (__bf16)v.x; ov[1] = (__bf16)v.y; ov[2] = (__bf16)v.z; ov[3] = (__bf16)v.w;
  *(bf16x4*)(o + i) = ov;
}

// ------------------------------------------------------------------ GEMM (BT)
// C[M,N] = A[M,K] * W[N,K]^T + bias.  128x128 tile, BK=32, 4 waves (2x2),
// m97-style global_load_lds staging. LDS tile [128][32], phys chunk (8 elems)
// p holds logical chunk p ^ (row&3) — DMA source chosen per lane to match;
// frag ds_read_b128 then lands at 8 distinct bank-starts per 8 lanes.
// z==0 (Q proj, !OUTF32): output scaled by QSCALE.
// z==2 (V proj): output written TRANSPOSED per (b): Vt[(b*1024+n)][s].
template <bool OUTF32>
__global__ __launch_bounds__(256) void gemm_bt(
    const __bf16* __restrict__ Abase, const __bf16* __restrict__ Wbase,
    const float* __restrict__ b0, const float* __restrict__ b1,
    const float* __restrict__ b2, void* __restrict__ Obase) {
  constexpr int K = 1024, N = 1024;
  const int z = blockIdx.z;
  const __bf16* A = Abase + (size_t)z * MROWS * K;
  const __bf16* W = Wbase + (size_t)z * N * K;
  const float* bias = (z == 0) ? b0 : (z == 1 ? b1 : b2);

  const int bm0 = blockIdx.x * 128, bn0 = blockIdx.y * 128;
  const int tid = threadIdx.x;
  const int lane = tid & 63, w = tid >> 6;
  const int wr = w >> 1, wc = w & 1;
  const int quad = lane >> 4, l15 = lane & 15;

  __shared__ __align__(16) __bf16 As[128 * 32];
  __shared__ __align__(16) __bf16 Bs[128 * 32];

  // DMA: call i covers rows i*64 + w*16 .. +16; lane -> row base+(l>>2),
  // phys chunk l&3, global chunk (l&3)^((l>>2)&3)
  const int drow = w * 16 + (lane >> 2);
  const int gch = (((lane & 3) ^ ((lane >> 2) & 3))) * 8;
  const __bf16* Ag0 = A + (size_t)(bm0 + drow) * K + gch;
  const __bf16* Ag1 = A + (size_t)(bm0 + drow + 64) * K + gch;
  const __bf16* Wg0 = W + (size_t)(bn0 + drow) * K + gch;
  const __bf16* Wg1 = W + (size_t)(bn0 + drow + 64) * K + gch;
  __bf16* lA0 = As + (w * 16) * 32;
  __bf16* lA1 = As + (64 + w * 16) * 32;
  __bf16* lB0 = Bs + (w * 16) * 32;
  __bf16* lB1 = Bs + (64 + w * 16) * 32;

  f32x4 acc[4][4];
  for (int i = 0; i < 4; i++)
    for (int j = 0; j < 4; j++) acc[i][j] = f32x4{0.f, 0.f, 0.f, 0.f};

  int aoff[4], boff[4];
  for (int i = 0; i < 4; i++) {
    aoff[i] = (wr * 64 + i * 16 + l15) * 32 + ((quad ^ (l15 & 3)) << 3);
    boff[i] = (wc * 64 + i * 16 + l15) * 32 + ((quad ^ (l15 & 3)) << 3);
  }

  for (int k0 = 0; k0 < K; k0 += 32) {
    __syncthreads();  // everyone done reading prev tile
    gll16(Ag0 + k0, lA0);
    gll16(Ag1 + k0, lA1);
    gll16(Wg0 + k0, lB0);
    gll16(Wg1 + k0, lB1);
    __syncthreads();  // vmcnt drain -> tile ready
    bf16x8 af[4], bfr[4];
    for (int i = 0; i < 4; i++) af[i] = *(const bf16x8*)(As + aoff[i]);
    for (int j = 0; j < 4; j++) bfr[j] = *(const bf16x8*)(Bs + boff[j]);
    for (int i = 0; i < 4; i++)
      for (int j = 0; j < 4; j++) acc[i][j] = MFMA16(af[i], bfr[j], acc[i][j]);
  }

  // epilogue: C/D layout col=lane&15, row=quad*4+reg
  if (!OUTF32 && z == 2) {
    // transposed V write: Vt[(b*1024 + n)][s], n = h*64+d, row = b*4096+s
    __bf16* Vt = ((__bf16*)Obase) + (size_t)2 * MROWS * N;
    for (int j = 0; j < 4; j++) {
      int n = bn0 + wc * 64 + j * 16 + l15;
      float bv = bias[n];
      for (int i = 0; i < 4; i++) {
        int grow0 = bm0 + wr * 64 + i * 16 + quad * 4;
        int bb = grow0 >> 12, s = grow0 & 4095;
        bf16x4 ov;
        for (int r = 0; r < 4; r++) ov[r] = (__bf16)(acc[i][j][r] + bv);
        *(bf16x4*)(Vt + ((size_t)(bb * 1024 + n)) * SEQ + s) = ov;
      }
    }
  } else {
    const float scale = (!OUTF32 && z == 0) ? QSCALE : 1.0f;
    for (int j = 0; j < 4; j++) {
      int gcol = bn0 + wc * 64 + j * 16 + l15;
      float bv = bias[gcol];
      for (int i = 0; i < 4; i++) {
        int grow0 = bm0 + wr * 64 + i * 16 + quad * 4;
        for (int r = 0; r < 4; r++) {
          float v = (acc[i][j][r] + bv) * scale;
          size_t idx = (size_t)(grow0 + r) * N + gcol;
          if constexpr (OUTF32)
            ((float*)Obase)[idx] = v;
          else
            (((__bf16*)Obase) + (size_t)z * MROWS * N)[idx] = (__bf16)v;
        }
      }
    }
  }
}

// ----------------------------------------------------------- flash attention
// grid (16, 16, 2), block 256 (4 waves). Wave w owns q cols [w*64, w*64+64).
// St = K*Q^T; O^T = V^T*P^T (stats per q = per lane, no cross-lane transform).
// K/V tiles 64x64 in LDS, double-buffered, staged via global_load_lds with
// swizzled source (phys chunk p at row r holds logical chunk p^(r&7)).
// One barrier per iter: barrier (drains tile kt DMA, issued one compute ago)
// -> issue DMA kt+1 into buf^1 -> compute kt from buf.
__global__ __launch_bounds__(256, 2) void attn_kernel(
    const __bf16* __restrict__ Q, const __bf16* __restrict__ K,
    const __bf16* __restrict__ Vt, __bf16* __restrict__ O) {
  const int qt = blockIdx.x, h = blockIdx.y, b = blockIdx.z;
  const __bf16* Qg = Q + ((size_t)b * SEQ + qt * QT) * D_MODEL + h * DKH;
  const __bf16* Kg = K + (size_t)b * SEQ * D_MODEL + h * DKH;
  const __bf16* Vg = Vt + ((size_t)b * D_MODEL + h * DKH) * SEQ;

  __shared__ __align__(16) __bf16 kvs[2][2 * 64 * 64];  // [buf][K tile | V tile]
  __shared__ __align__(16) __bf16 Ps[QT * LROW];        // P, per-wave 64-row bands

  const int tid = threadIdx.x;
  const int lane = tid & 63, w = tid >> 6;
  const int quad = lane >> 4, l15 = lane & 15;

  // DMA lane constants: call i covers tile rows i*32 + w*8 .. +8
  const int dr = lane >> 3;                       // row within 8-row group
  const int dch = ((lane & 7) ^ (dr & 7)) * 8;    // swizzled global chunk (elems)
  const __bf16* KgT = Kg + (size_t)(w * 8 + dr) * D_MODEL + dch;
  const __bf16* VgT = Vg + (size_t)(w * 8 + dr) * SEQ + dch;
  const int ldsb = (w * 8) * 64;  // wave-uniform LDS offset (elems)

  // Q frags direct from global: B[k=d=quad*8+j+32ks][n=q=w*64+16jq+l15]
  bf16x8 qf[4][2];
  for (int jq = 0; jq < 4; jq++)
    for (int ks = 0; ks < 2; ks++)
      qf[jq][ks] = *(const bf16x8*)(
          Qg + (size_t)(w * 64 + jq * 16 + l15) * D_MODEL + (quad + 4 * ks) * 8);

  // issue tile 0 DMA
  gll16(KgT, &kvs[0][ldsb]);
  gll16(KgT + (size_t)32 * D_MODEL, &kvs[0][32 * 64 + ldsb]);
  gll16(VgT, &kvs[0][4096 + ldsb]);
  gll16(VgT + (size_t)32 * SEQ, &kvs[0][4096 + 32 * 64 + ldsb]);

  float m_[4], l_[4];
  f32x4 o_[4][4];  // o_[id][jq]: O^T[d=16id+quad*4+r][q=w*64+16jq+l15]
  for (int jq = 0; jq < 4; jq++) { m_[jq] = -__builtin_inff(); l_[jq] = 0.f; }
  for (int id = 0; id < 4; id++)
    for (int jq = 0; jq < 4; jq++) o_[id][jq] = f32x4{0.f, 0.f, 0.f, 0.f};

  for (int kt = 0; kt < SEQ / 64; ++kt) {
    __syncthreads();  // drains tile kt DMA; all done reading buf^1
    const __bf16* Ks = kvs[kt & 1];
    const __bf16* Vts = Ks + 4096;
    if (kt != SEQ / 64 - 1) {  // prefetch tile kt+1 into other buffer
      const __bf16* kg = KgT + (size_t)(kt + 1) * 64 * D_MODEL;
      const __bf16* vg = VgT + (kt + 1) * 64;
      __bf16* dK = &kvs[(kt + 1) & 1][ldsb];
      __bf16* dV = &kvs[(kt + 1) & 1][4096 + ldsb];
      gll16(kg, dK);
      gll16(kg + (size_t)32 * D_MODEL, dK + 32 * 64);
      gll16(vg, dV);
      gll16(vg + (size_t)32 * SEQ, dV + 32 * 64);
    }

    // St[kv][q] = K * Q^T  (Q pre-scaled by log2e/8)
    f32x4 st[4][4];  // st[i][jq]: kv = 16i+quad*4+r, q = 16jq+l15
    for (int i = 0; i < 4; i++) {
      bf16x8 kf0 = *(const bf16x8*)(Ks + (i * 16 + l15) * 64 +
                                    ((quad ^ (l15 & 7)) << 3));
      bf16x8 kf1 = *(const bf16x8*)(Ks + (i * 16 + l15) * 64 +
                                    (((quad + 4) ^ (l15 & 7)) << 3));
      for (int jq = 0; jq < 4; jq++) {
        f32x4 c = f32x4{0.f, 0.f, 0.f, 0.f};
        c = MFMA16(kf0, qf[jq][0], c);
        c = MFMA16(kf1, qf[jq][1], c);
        st[i][jq] = c;
      }
    }

    // online softmax per q-column, exp2 domain
    for (int jq = 0; jq < 4; jq++) {
      float mx = st[0][jq][0];
      for (int i = 0; i < 4; i++)
        for (int r = 0; r < 4; r++) mx = fmaxf(mx, st[i][jq][r]);
      mx = fmaxf(mx, __shfl_xor(mx, 16));
      mx = fmaxf(mx, __shfl_xor(mx, 32));
      if (__any(mx > m_[jq])) {  // rescale history only when max renews
        float mn = fmaxf(m_[jq], mx);
        float al = exp2f(m_[jq] - mn);
        m_[jq] = mn;
        l_[jq] *= al;
        for (int id = 0; id < 4; id++) o_[id][jq] *= al;
      }
      float mn = m_[jq];
      float rs = 0.f;
      for (int i = 0; i < 4; i++)
        for (int r = 0; r < 4; r++) {
          float p = exp2f(st[i][jq][r] - mn);
          st[i][jq][r] = p;
          rs += p;
        }
      rs += __shfl_xor(rs, 16);
      rs += __shfl_xor(rs, 32);
      l_[jq] += rs;
      // write P[q][kv], wave-private rows: 4 consecutive kv per b64
      int prow = w * 64 + jq * 16 + l15;
      for (int i = 0; i < 4; i++) {
        bf16x4 pv;
        for (int r = 0; r < 4; r++) pv[r] = (__bf16)st[i][jq][r];
        *(bf16x4*)(Ps + prow * LROW + i * 16 + quad * 4) = pv;
      }
    }
    asm volatile("s_waitcnt lgkmcnt(0)" ::: "memory");  // P visible to own wave

    // O^T += V^T * P^T
    for (int ks = 0; ks < 2; ks++) {
      bf16x8 pb[4];
      for (int jq = 0; jq < 4; jq++)
        pb[jq] = *(const bf16x8*)(Ps + (w * 64 + jq * 16 + l15) * LROW +
                                  (quad + 4 * ks) * 8);
      for (int id = 0; id < 4; id++) {
        bf16x8 va = *(const bf16x8*)(Vts + (id * 16 + l15) * 64 +
                                     (((quad + 4 * ks) ^ (l15 & 7)) << 3));
        for (int jq = 0; jq < 4; jq++)
          o_[id][jq] = MFMA16(va, pb[jq], o_[id][jq]);
      }
    }
  }

  // epilogue: O^T[d][q] -> AO[q_global][h*64+d], /l, packed b64 stores
  for (int jq = 0; jq < 4; jq++) {
    float inv = 1.f / l_[jq];
    int grow = qt * QT + w * 64 + jq * 16 + l15;
    __bf16* og = O + ((size_t)b * SEQ + grow) * D_MODEL + h * DKH;
    for (int id = 0; id < 4; id++) {
      bf16x4 ov;
      for (int r = 0; r < 4; r++) ov[r] = (__bf16)(o_[id][jq][r] * inv);
      *(bf16x4*)(og + id * 16 + quad * 4) = ov;
    }
  }
}

// ---------------------------------------------------------------------------
extern "C" void kernel_launch(void* const* d_in, const int* in_sizes, int n_in,
                              void* d_out, int out_size, void* d_ws,
                              size_t ws_size, hipStream_t stream) {
  const float* q  = (const float*)d_in[0];
  const float* k  = (const float*)d_in[1];
  const float* v  = (const float*)d_in[2];
  const float* Wq = (const float*)d_in[3];
  const float* bq = (const float*)d_in[4];
  const float* Wk = (const float*)d_in[5];
  const float* bk = (const float*)d_in[6];
  const float* Wv = (const float*)d_in[7];
  const float* bv = (const float*)d_in[8];
  const float* Wo = (const float*)d_in[9];
  const float* bo = (const float*)d_in[10];

  const size_t MD = (size_t)MROWS * D_MODEL;
  const size_t WW = (size_t)D_MODEL * D_MODEL;

  __bf16* ws  = (__bf16*)d_ws;
  __bf16* Xq  = ws;                // Xq,Xk,Xv contiguous
  __bf16* Wqb = Xq + 3 * MD;       // Wq,Wk,Wv,Wo contiguous
  __bf16* Qp  = Wqb + 4 * WW;      // z=0 Q (scaled), z=1 K, z=2 V^T
  __bf16* Kp  = Qp + MD;
  __bf16* Vtp = Kp + MD;           // transposed: [(b*1024 + h*64 + d)][s]
  __bf16* AO  = Vtp + MD;

  cast_x3<<<dim3(8192, 3), 256, 0, stream>>>(q, k, v, Xq);
  cast_w4<<<dim3(1024, 4), 256, 0, stream>>>(Wq, Wk, Wv, Wo, Wqb);

  // fused QKV projections: z=0 Q(scaled log2e/8), z=1 K, z=2 V^T
  gemm_bt<false><<<dim3(MROWS / 128, D_MODEL / 128, 3), 256, 0, stream>>>(
      Xq, Wqb, bq, bk, bv, (void*)Qp);

  attn_kernel<<<dim3(SEQ / QT, 16, BATCH), 256, 0, stream>>>(Qp, Kp, Vtp, AO);

  gemm_bt<true><<<dim3(MROWS / 128, D_MODEL / 128, 1), 256, 0, stream>>>(
      AO, Wqb + 3 * WW, bo, bo, bo, d_out);
}

// Round 4
// 434.091 us; speedup vs baseline: 1.2058x; 1.2058x over previous
//
#include <hip/hip_runtime.h>

// ---------------------------------------------------------------------------
// MHA forward. B=2 S=4096 D=1024 H=16 DK=64. bf16 MFMA 16x16x32, fp32 acc.
// R4: R3 structure + raw v_exp_f32 (R3 regressed via slow ocml exp2f),
// row-sum l via ones-MFMA (softmax sum moved off the VALU pipe),
// strength-reduced DMA pointers.
// ---------------------------------------------------------------------------

typedef __bf16 bf16x8 __attribute__((ext_vector_type(8)));
typedef __bf16 bf16x4 __attribute__((ext_vector_type(4)));
typedef float  f32x4  __attribute__((ext_vector_type(4)));

#define MFMA16(a, b, c) __builtin_amdgcn_mfma_f32_16x16x32_bf16(a, b, c, 0, 0, 0)

constexpr int D_MODEL = 1024;
constexpr int SEQ     = 4096;
constexpr int BATCH   = 2;
constexpr int DKH     = 64;
constexpr int MROWS   = BATCH * SEQ;  // 8192
constexpr int QT      = 256;          // q rows per attn block
constexpr int LROW    = 72;           // padded LDS row stride for Ps
// softmax in exp2 domain: fold 1/sqrt(64) * log2(e) into Q projection
constexpr float QSCALE = 0.125f * 1.4426950408889634f;

__device__ __forceinline__ float fexp2(float x) {
#if __has_builtin(__builtin_amdgcn_exp2f)
  return __builtin_amdgcn_exp2f(x);  // raw v_exp_f32 (1 instr, flush-denorm ok)
#else
  return exp2f(x);
#endif
}

__device__ __forceinline__ void gll16(const void* g, void* l) {
  __builtin_amdgcn_global_load_lds(
      (const __attribute__((address_space(1))) void*)g,
      (__attribute__((address_space(3))) void*)l, 16, 0, 0);
}

// ---------------------------------------------------------------- cast kernels
__global__ void cast_x3(const float* __restrict__ a, const float* __restrict__ b,
                        const float* __restrict__ c, __bf16* __restrict__ out) {
  const float* in = blockIdx.y == 0 ? a : (blockIdx.y == 1 ? b : c);
  __bf16* o = out + (size_t)blockIdx.y * MROWS * D_MODEL;
  int i = (blockIdx.x * 256 + threadIdx.x) * 4;
  float4 v = *(const float4*)(in + i);
  bf16x4 ov;
  ov[0] = (__bf16)v.x; ov[1] = (__bf16)v.y; ov[2] = (__bf16)v.z; ov[3] = (__bf16)v.w;
  *(bf16x4*)(o + i) = ov;
}

__global__ void cast_w4(const float* __restrict__ a, const float* __restrict__ b,
                        const float* __restrict__ c, const float* __restrict__ d,
                        __bf16* __restrict__ out) {
  const float* in = blockIdx.y == 0 ? a
                    : (blockIdx.y == 1 ? b : (blockIdx.y == 2 ? c : d));
  __bf16* o = out + (size_t)blockIdx.y * D_MODEL * D_MODEL;
  int i = (blockIdx.x * 256 + threadIdx.x) * 4;
  float4 v = *(const float4*)(in + i);
  bf16x4 ov;
  ov[0] = (__bf16)v.x; ov[1] = (__bf16)v.y; ov[2] = (__bf16)v.z; ov[3] = (__bf16)v.w;
  *(bf16x4*)(o + i) = ov;
}

// ------------------------------------------------------------------ GEMM (BT)
// C[M,N] = A[M,K] * W[N,K]^T + bias.  128x128 tile, BK=32, 4 waves (2x2),
// m97-style global_load_lds staging with swizzled per-lane source chunks.
// z==0 (Q proj, !OUTF32): output scaled by QSCALE.
// z==2 (V proj): output written TRANSPOSED per (b): Vt[(b*1024+n)][s].
template <bool OUTF32>
__global__ __launch_bounds__(256) void gemm_bt(
    const __bf16* __restrict__ Abase, const __bf16* __restrict__ Wbase,
    const float* __restrict__ b0, const float* __restrict__ b1,
    const float* __restrict__ b2, void* __restrict__ Obase) {
  constexpr int K = 1024, N = 1024;
  const int z = blockIdx.z;
  const __bf16* A = Abase + (size_t)z * MROWS * K;
  const __bf16* W = Wbase + (size_t)z * N * K;
  const float* bias = (z == 0) ? b0 : (z == 1 ? b1 : b2);

  const int bm0 = blockIdx.x * 128, bn0 = blockIdx.y * 128;
  const int tid = threadIdx.x;
  const int lane = tid & 63, w = tid >> 6;
  const int wr = w >> 1, wc = w & 1;
  const int quad = lane >> 4, l15 = lane & 15;

  __shared__ __align__(16) __bf16 As[128 * 32];
  __shared__ __align__(16) __bf16 Bs[128 * 32];

  const int drow = w * 16 + (lane >> 2);
  const int gch = (((lane & 3) ^ ((lane >> 2) & 3))) * 8;
  const __bf16* Ag0 = A + (size_t)(bm0 + drow) * K + gch;
  const __bf16* Ag1 = A + (size_t)(bm0 + drow + 64) * K + gch;
  const __bf16* Wg0 = W + (size_t)(bn0 + drow) * K + gch;
  const __bf16* Wg1 = W + (size_t)(bn0 + drow + 64) * K + gch;
  __bf16* lA0 = As + (w * 16) * 32;
  __bf16* lA1 = As + (64 + w * 16) * 32;
  __bf16* lB0 = Bs + (w * 16) * 32;
  __bf16* lB1 = Bs + (64 + w * 16) * 32;

  f32x4 acc[4][4];
  for (int i = 0; i < 4; i++)
    for (int j = 0; j < 4; j++) acc[i][j] = f32x4{0.f, 0.f, 0.f, 0.f};

  int aoff[4], boff[4];
  for (int i = 0; i < 4; i++) {
    aoff[i] = (wr * 64 + i * 16 + l15) * 32 + ((quad ^ (l15 & 3)) << 3);
    boff[i] = (wc * 64 + i * 16 + l15) * 32 + ((quad ^ (l15 & 3)) << 3);
  }

  for (int k0 = 0; k0 < K; k0 += 32) {
    __syncthreads();
    gll16(Ag0 + k0, lA0);
    gll16(Ag1 + k0, lA1);
    gll16(Wg0 + k0, lB0);
    gll16(Wg1 + k0, lB1);
    __syncthreads();
    bf16x8 af[4], bfr[4];
    for (int i = 0; i < 4; i++) af[i] = *(const bf16x8*)(As + aoff[i]);
    for (int j = 0; j < 4; j++) bfr[j] = *(const bf16x8*)(Bs + boff[j]);
    for (int i = 0; i < 4; i++)
      for (int j = 0; j < 4; j++) acc[i][j] = MFMA16(af[i], bfr[j], acc[i][j]);
  }

  if (!OUTF32 && z == 2) {
    __bf16* Vt = ((__bf16*)Obase) + (size_t)2 * MROWS * N;
    for (int j = 0; j < 4; j++) {
      int n = bn0 + wc * 64 + j * 16 + l15;
      float bv = bias[n];
      for (int i = 0; i < 4; i++) {
        int grow0 = bm0 + wr * 64 + i * 16 + quad * 4;
        int bb = grow0 >> 12, s = grow0 & 4095;
        bf16x4 ov;
        for (int r = 0; r < 4; r++) ov[r] = (__bf16)(acc[i][j][r] + bv);
        *(bf16x4*)(Vt + ((size_t)(bb * 1024 + n)) * SEQ + s) = ov;
      }
    }
  } else {
    const float scale = (!OUTF32 && z == 0) ? QSCALE : 1.0f;
    for (int j = 0; j < 4; j++) {
      int gcol = bn0 + wc * 64 + j * 16 + l15;
      float bv = bias[gcol];
      for (int i = 0; i < 4; i++) {
        int grow0 = bm0 + wr * 64 + i * 16 + quad * 4;
        for (int r = 0; r < 4; r++) {
          float v = (acc[i][j][r] + bv) * scale;
          size_t idx = (size_t)(grow0 + r) * N + gcol;
          if constexpr (OUTF32)
            ((float*)Obase)[idx] = v;
          else
            (((__bf16*)Obase) + (size_t)z * MROWS * N)[idx] = (__bf16)v;
        }
      }
    }
  }
}

// ----------------------------------------------------------- flash attention
// grid (16, 16, 2), block 256 (4 waves). Wave w owns q cols [w*64, w*64+64).
// St = K*Q^T; O^T = V^T*P^T.  K/V 64x64 tiles double-buffered via
// global_load_lds (swizzled source chunks), ONE barrier/iter.
// l accumulated as an extra ones-row MFMA on the matrix pipe.
__global__ __launch_bounds__(256, 2) void attn_kernel(
    const __bf16* __restrict__ Q, const __bf16* __restrict__ K,
    const __bf16* __restrict__ Vt, __bf16* __restrict__ O) {
  const int qt = blockIdx.x, h = blockIdx.y, b = blockIdx.z;
  const __bf16* Qg = Q + ((size_t)b * SEQ + qt * QT) * D_MODEL + h * DKH;
  const __bf16* Kg = K + (size_t)b * SEQ * D_MODEL + h * DKH;
  const __bf16* Vg = Vt + ((size_t)b * D_MODEL + h * DKH) * SEQ;

  __shared__ __align__(16) __bf16 kvs[2][2 * 64 * 64];  // [buf][K | V]
  __shared__ __align__(16) __bf16 Ps[QT * LROW];

  const int tid = threadIdx.x;
  const int lane = tid & 63, w = tid >> 6;
  const int quad = lane >> 4, l15 = lane & 15;

  const int dr = lane >> 3;
  const int dch = ((lane & 7) ^ (dr & 7)) * 8;
  const __bf16* KgT = Kg + (size_t)(w * 8 + dr) * D_MODEL + dch;
  const __bf16* VgT = Vg + (size_t)(w * 8 + dr) * SEQ + dch;
  const int ldsb = (w * 8) * 64;

  // Q frags direct from global: B[k=d=quad*8+j+32ks][n=q=w*64+16jq+l15]
  bf16x8 qf[4][2];
  for (int jq = 0; jq < 4; jq++)
    for (int ks = 0; ks < 2; ks++)
      qf[jq][ks] = *(const bf16x8*)(
          Qg + (size_t)(w * 64 + jq * 16 + l15) * D_MODEL + (quad + 4 * ks) * 8);

  // ones A-frag for the l row-sum MFMA
  bf16x8 onesf;
  for (int j = 0; j < 8; j++) onesf[j] = (__bf16)1.0f;

  // issue tile 0 DMA; keep incrementing source pointers
  gll16(KgT, &kvs[0][ldsb]);
  gll16(KgT + (size_t)32 * D_MODEL, &kvs[0][32 * 64 + ldsb]);
  gll16(VgT, &kvs[0][4096 + ldsb]);
  gll16(VgT + (size_t)32 * SEQ, &kvs[0][4096 + 32 * 64 + ldsb]);
  const __bf16* kgp = KgT + (size_t)64 * D_MODEL;
  const __bf16* vgp = VgT + 64;

  float m_[4];
  f32x4 o_[4][4];  // o_[id][jq]: O^T[d=16id+quad*4+r][q=w*64+16jq+l15]
  f32x4 ol_[4];    // ol_[jq][0]: running sum l for q=w*64+16jq+l15
  for (int jq = 0; jq < 4; jq++) { m_[jq] = -__builtin_inff(); ol_[jq] = f32x4{0,0,0,0}; }
  for (int id = 0; id < 4; id++)
    for (int jq = 0; jq < 4; jq++) o_[id][jq] = f32x4{0.f, 0.f, 0.f, 0.f};

  for (int kt = 0; kt < SEQ / 64; ++kt) {
    __syncthreads();  // drains tile kt DMA (issued one compute-phase ago)
    const __bf16* Ks = kvs[kt & 1];
    const __bf16* Vts = Ks + 4096;
    if (kt != SEQ / 64 - 1) {
      __bf16* dK = &kvs[(kt + 1) & 1][ldsb];
      __bf16* dV = &kvs[(kt + 1) & 1][4096 + ldsb];
      gll16(kgp, dK);
      gll16(kgp + (size_t)32 * D_MODEL, dK + 32 * 64);
      gll16(vgp, dV);
      gll16(vgp + (size_t)32 * SEQ, dV + 32 * 64);
      kgp += (size_t)64 * D_MODEL;
      vgp += 64;
    }

    // St[kv][q] = K * Q^T  (Q pre-scaled by log2e/8)
    f32x4 st[4][4];  // st[i][jq]: kv = 16i+quad*4+r, q = 16jq+l15
    for (int i = 0; i < 4; i++) {
      bf16x8 kf0 = *(const bf16x8*)(Ks + (i * 16 + l15) * 64 +
                                    ((quad ^ (l15 & 7)) << 3));
      bf16x8 kf1 = *(const bf16x8*)(Ks + (i * 16 + l15) * 64 +
                                    (((quad + 4) ^ (l15 & 7)) << 3));
      for (int jq = 0; jq < 4; jq++) {
        f32x4 c = f32x4{0.f, 0.f, 0.f, 0.f};
        c = MFMA16(kf0, qf[jq][0], c);
        c = MFMA16(kf1, qf[jq][1], c);
        st[i][jq] = c;
      }
    }

    // online softmax per q-column, exp2 domain (sum deferred to ones-MFMA)
    for (int jq = 0; jq < 4; jq++) {
      float mx = fmaxf(fmaxf(st[0][jq][0], st[0][jq][1]),
                       fmaxf(st[0][jq][2], st[0][jq][3]));
      for (int i = 1; i < 4; i++)
        for (int r = 0; r < 4; r++) mx = fmaxf(mx, st[i][jq][r]);
      mx = fmaxf(mx, __shfl_xor(mx, 16));
      mx = fmaxf(mx, __shfl_xor(mx, 32));
      if (__any(mx > m_[jq])) {  // rescale history only when max renews
        float mn = fmaxf(m_[jq], mx);
        float al = fexp2(m_[jq] - mn);
        m_[jq] = mn;
        ol_[jq][0] *= al;  // only elem 0 is ever read (independent chains)
        for (int id = 0; id < 4; id++) o_[id][jq] *= al;
      }
      float mn = m_[jq];
      int prow = w * 64 + jq * 16 + l15;
      for (int i = 0; i < 4; i++) {
        bf16x4 pv;
        for (int r = 0; r < 4; r++) pv[r] = (__bf16)fexp2(st[i][jq][r] - mn);
        *(bf16x4*)(Ps + prow * LROW + i * 16 + quad * 4) = pv;
      }
    }
    asm volatile("s_waitcnt lgkmcnt(0)" ::: "memory");  // P visible to own wave

    // O^T += V^T * P^T ; l += ones * P^T (row-sum on the MFMA pipe)
    for (int ks = 0; ks < 2; ks++) {
      bf16x8 pb[4];
      for (int jq = 0; jq < 4; jq++)
        pb[jq] = *(const bf16x8*)(Ps + (w * 64 + jq * 16 + l15) * LROW +
                                  (quad + 4 * ks) * 8);
      for (int jq = 0; jq < 4; jq++) ol_[jq] = MFMA16(onesf, pb[jq], ol_[jq]);
      for (int id = 0; id < 4; id++) {
        bf16x8 va = *(const bf16x8*)(Vts + (id * 16 + l15) * 64 +
                                     (((quad + 4 * ks) ^ (l15 & 7)) << 3));
        for (int jq = 0; jq < 4; jq++)
          o_[id][jq] = MFMA16(va, pb[jq], o_[id][jq]);
      }
    }
  }

  // epilogue: O^T[d][q] -> AO[q_global][h*64+d], /l, packed b64 stores
  for (int jq = 0; jq < 4; jq++) {
    float inv = 1.f / ol_[jq][0];
    int grow = qt * QT + w * 64 + jq * 16 + l15;
    __bf16* og = O + ((size_t)b * SEQ + grow) * D_MODEL + h * DKH;
    for (int id = 0; id < 4; id++) {
      bf16x4 ov;
      for (int r = 0; r < 4; r++) ov[r] = (__bf16)(o_[id][jq][r] * inv);
      *(bf16x4*)(og + id * 16 + quad * 4) = ov;
    }
  }
}

// ---------------------------------------------------------------------------
extern "C" void kernel_launch(void* const* d_in, const int* in_sizes, int n_in,
                              void* d_out, int out_size, void* d_ws,
                              size_t ws_size, hipStream_t stream) {
  const float* q  = (const float*)d_in[0];
  const float* k  = (const float*)d_in[1];
  const float* v  = (const float*)d_in[2];
  const float* Wq = (const float*)d_in[3];
  const float* bq = (const float*)d_in[4];
  const float* Wk = (const float*)d_in[5];
  const float* bk = (const float*)d_in[6];
  const float* Wv = (const float*)d_in[7];
  const float* bv = (const float*)d_in[8];
  const float* Wo = (const float*)d_in[9];
  const float* bo = (const float*)d_in[10];

  const size_t MD = (size_t)MROWS * D_MODEL;
  const size_t WW = (size_t)D_MODEL * D_MODEL;

  __bf16* ws  = (__bf16*)d_ws;
  __bf16* Xq  = ws;                // Xq,Xk,Xv contiguous
  __bf16* Wqb = Xq + 3 * MD;       // Wq,Wk,Wv,Wo contiguous
  __bf16* Qp  = Wqb + 4 * WW;      // z=0 Q (scaled), z=1 K, z=2 V^T
  __bf16* Kp  = Qp + MD;
  __bf16* Vtp = Kp + MD;           // transposed: [(b*1024 + h*64 + d)][s]
  __bf16* AO  = Vtp + MD;

  cast_x3<<<dim3(8192, 3), 256, 0, stream>>>(q, k, v, Xq);
  cast_w4<<<dim3(1024, 4), 256, 0, stream>>>(Wq, Wk, Wv, Wo, Wqb);

  gemm_bt<false><<<dim3(MROWS / 128, D_MODEL / 128, 3), 256, 0, stream>>>(
      Xq, Wqb, bq, bk, bv, (void*)Qp);

  attn_kernel<<<dim3(SEQ / QT, 16, BATCH), 256, 0, stream>>>(Qp, Kp, Vtp, AO);

  gemm_bt<true><<<dim3(MROWS / 128, D_MODEL / 128, 1), 256, 0, stream>>>(
      AO, Wqb + 3 * WW, bo, bo, bo, d_out);
}